// Round 9
// baseline (264.196 us; speedup 1.0000x reference)
//
#include <hip/hip_runtime.h>

// EdgeGATConv: h = x@fc_w^T + fc_b;  alpha = leaky_relu(Wi@h[src] + Wj@h[dst] + We@ea + att_b)
// out[src] += h[dst] * alpha
// N=50000, C=128, H=64, E_DIM=16, E=800000
//
// R9: measurement round. R8 fused the src-histogram into node_kernel and node
// went 30->91us (unexplained; 800K atomics should be ~3us). Un-fuse it, change
// NOTHING else, so the profile shows node/hist/scatter/csr_edge separately.
// Edge phase wall (established R6-R8): random-gather BW ~2TB/s, bytes-linear.

__device__ __forceinline__ unsigned bf16r(float f) {  // f32 -> bf16 bits (RNE)
    unsigned u = __float_as_uint(f);
    return (u + 0x7fffu + ((u >> 16) & 1u)) >> 16;
}
__device__ __forceinline__ float bf_lo(unsigned p) { return __uint_as_float(p << 16); }
__device__ __forceinline__ float bf_hi(unsigned p) { return __uint_as_float(p & 0xffff0000u); }

// ---------------- node kernel (R1-proven shape, bf16-packed hj out) ---------
__global__ __launch_bounds__(256) void node_kernel(
    const float* __restrict__ x,
    const float* __restrict__ fc_w, const float* __restrict__ fc_b,
    const float* __restrict__ att_w, const float* __restrict__ att_b,
    float* __restrict__ ai_out, unsigned* __restrict__ hj_out, int N)
{
    __shared__ __align__(16) float4 wF[64 * 32];  // fc_w rows [64][128]
    __shared__ __align__(16) float4 wI[64 * 16];  // att_w[:, 0:64]
    __shared__ __align__(16) float4 wJ[64 * 16];  // att_w[:, 64:128]
    __shared__ __align__(16) float xs[4][128];
    __shared__ __align__(16) float hs[4][64];

    const int t = threadIdx.x;
    for (int idx = t; idx < 64 * 32; idx += 256) {
        int l = idx >> 5, c = idx & 31;
        wF[l * 32 + (c ^ (l & 31))] =
            *reinterpret_cast<const float4*>(fc_w + l * 128 + c * 4);
    }
    for (int idx = t; idx < 64 * 16; idx += 256) {
        int l = idx >> 4, c = idx & 15;
        wI[l * 16 + (c ^ (l & 15))] =
            *reinterpret_cast<const float4*>(att_w + l * 144 + c * 4);
        wJ[l * 16 + (c ^ (l & 15))] =
            *reinterpret_cast<const float4*>(att_w + l * 144 + 64 + c * 4);
    }
    __syncthreads();

    const int w = t >> 6, l = t & 63;
    const float bF = fc_b[l];
    const float bA = att_b[l];   // fold att_b into a_i
    const int waveId = blockIdx.x * 4 + w;
    const int nWaves = gridDim.x * 4;

    for (int n = waveId; n < N; n += nWaves) {
        float2 xv = reinterpret_cast<const float2*>(x)[(size_t)n * 64 + l];
        xs[w][2 * l] = xv.x;
        xs[w][2 * l + 1] = xv.y;
        float acc = bF;
        #pragma unroll
        for (int c = 0; c < 32; ++c) {
            float4 wv = wF[l * 32 + (c ^ (l & 31))];
            float4 xc = *reinterpret_cast<const float4*>(&xs[w][c * 4]);
            acc = fmaf(wv.x, xc.x, acc);
            acc = fmaf(wv.y, xc.y, acc);
            acc = fmaf(wv.z, xc.z, acc);
            acc = fmaf(wv.w, xc.w, acc);
        }
        hs[w][l] = acc;
        float a2 = bA, a3 = 0.f;
        #pragma unroll
        for (int c = 0; c < 16; ++c) {
            float4 hvv = *reinterpret_cast<const float4*>(&hs[w][c * 4]);
            float4 wi = wI[l * 16 + (c ^ (l & 15))];
            float4 wj = wJ[l * 16 + (c ^ (l & 15))];
            a2 = fmaf(wi.x, hvv.x, a2); a2 = fmaf(wi.y, hvv.y, a2);
            a2 = fmaf(wi.z, hvv.z, a2); a2 = fmaf(wi.w, hvv.w, a2);
            a3 = fmaf(wj.x, hvv.x, a3); a3 = fmaf(wj.y, hvv.y, a3);
            a3 = fmaf(wj.z, hvv.z, a3); a3 = fmaf(wj.w, hvv.w, a3);
        }
        ai_out[(size_t)n * 64 + l] = a2;
        // pack {h, aj} as bf16 pair: low=h, high=aj -> one dword gather/edge
        hj_out[(size_t)n * 64 + l] = (bf16r(a3) << 16) | bf16r(acc);
    }
}

// ---------------- src histogram (standalone, as in R7) ----------------------
__global__ __launch_bounds__(256) void hist_kernel(
    const int* __restrict__ ei, int* __restrict__ count, int E)
{
    int i = blockIdx.x * 256 + threadIdx.x;
    int stride = gridDim.x * 256;
    for (; i < E; i += stride) atomicAdd(&count[ei[i]], 1);
}

// ------------- single-block exclusive scan (1 launch) -----------------------
__global__ __launch_bounds__(1024) void scan_kernel(
    const int* __restrict__ count, int* __restrict__ start, int N)
{
    __shared__ int wsums[16];
    const int t = threadIdx.x, lane = t & 63, w = t >> 6;
    int carry = 0;
    for (int base = 0; base < N; base += 1024) {
        int i = base + t;
        int c = (i < N) ? count[i] : 0;
        int v = c;
        #pragma unroll
        for (int off = 1; off < 64; off <<= 1) {
            int u = __shfl_up(v, off);
            if (lane >= off) v += u;
        }
        if (lane == 63) wsums[w] = v;
        __syncthreads();
        int wbase = 0, total = 0;
        #pragma unroll
        for (int q = 0; q < 16; ++q) {
            int s = wsums[q];
            if (q < w) wbase += s;
            total += s;
        }
        if (i < N) start[i] = carry + wbase + v - c;
        carry += total;
        __syncthreads();
    }
}

// scatter: sd[pos]=dst; ea row -> bf16-packed, written in CSR order.
// atomicAdd on start[] itself (becomes end-pointer; edge kernel recomputes
// base = end - deg).
__global__ __launch_bounds__(256) void scatter_kernel(
    const int* __restrict__ ei, int* __restrict__ start,
    int* __restrict__ sd, uint4* __restrict__ eaS,   // [E][2] uint4 (8 u32/row)
    const float4* __restrict__ ea4, int E)
{
    int i = blockIdx.x * 256 + threadIdx.x;
    int stride = gridDim.x * 256;
    for (; i < E; i += stride) {
        int s = ei[i];
        int pos = atomicAdd(&start[s], 1);
        sd[pos] = ei[E + i];
        float4 r0 = ea4[(size_t)i * 4 + 0], r1 = ea4[(size_t)i * 4 + 1];
        float4 r2 = ea4[(size_t)i * 4 + 2], r3 = ea4[(size_t)i * 4 + 3];
        uint4 q0 = make_uint4((bf16r(r0.y) << 16) | bf16r(r0.x),
                              (bf16r(r0.w) << 16) | bf16r(r0.z),
                              (bf16r(r1.y) << 16) | bf16r(r1.x),
                              (bf16r(r1.w) << 16) | bf16r(r1.z));
        uint4 q1 = make_uint4((bf16r(r2.y) << 16) | bf16r(r2.x),
                              (bf16r(r2.w) << 16) | bf16r(r2.z),
                              (bf16r(r3.y) << 16) | bf16r(r3.x),
                              (bf16r(r3.w) << 16) | bf16r(r3.z));
        eaS[(size_t)pos * 2 + 0] = q0;
        eaS[(size_t)pos * 2 + 1] = q1;
    }
}

// --------- CSR edge kernel: 1 wave/node, 1 dword gather/edge, 0 atomics -----
__global__ __launch_bounds__(256) void csr_edge_kernel(
    const int* __restrict__ sd, const uint2* __restrict__ eaS2,  // [E][4] uint2
    const int* __restrict__ endp, const int* __restrict__ count,
    const float* __restrict__ ai, const unsigned* __restrict__ hj,
    const float* __restrict__ att_w, float* __restrict__ out, int N)
{
    __shared__ uint2 eas[4][256];     // per wave: 64 edges x 8 u32 (bf16 rows)
    __shared__ float weS[64][17];     // att_w[:,128:144], padded (stride 17)

    const int t = threadIdx.x, w = t >> 6, l = t & 63;
    for (int idx = t; idx < 1024; idx += 256)
        weS[idx >> 4][idx & 15] = att_w[(idx >> 4) * 144 + 128 + (idx & 15)];
    __syncthreads();

    const int n = blockIdx.x * 4 + w;
    if (n >= N) return;

    float we[16];
    #pragma unroll
    for (int k = 0; k < 16; ++k) we[k] = weS[l][k];

    const int deg = count[n];
    const int base = endp[n] - deg;    // endp was advanced by scatter
    const float aiv = ai[(size_t)n * 64 + l];
    float acc = 0.f;

#define EDGE_BODY(KK, UU)                                                      \
    {                                                                          \
        float pre = aiv + bf_hi(UU);                                           \
        _Pragma("unroll") for (int r = 0; r < 4; ++r) {                        \
            uint2 q = eas[w][(KK) * 4 + r];                                    \
            pre = fmaf(we[r * 4 + 0], bf_lo(q.x), pre);                        \
            pre = fmaf(we[r * 4 + 1], bf_hi(q.x), pre);                        \
            pre = fmaf(we[r * 4 + 2], bf_lo(q.y), pre);                        \
            pre = fmaf(we[r * 4 + 3], bf_hi(q.y), pre);                        \
        }                                                                      \
        float alpha = pre > 0.f ? pre : 0.2f * pre;                            \
        acc = fmaf(bf_lo(UU), alpha, acc);                                     \
    }

    int done = 0;
    while (done < deg) {
        const int rem = min(64, deg - done);
        int v = 0;
        if (l < rem) v = sd[base + done + l];
        for (int f = l; f < rem * 4; f += 64)          // stage ea rows (stream)
            eas[w][f] = eaS2[(size_t)(base + done) * 4 + f];
        int k = 0;
        for (; k + 8 <= rem; k += 8) {                 // 8 gathers in flight
            int d[8]; unsigned u[8];
            #pragma unroll
            for (int j = 0; j < 8; ++j) {
                d[j] = __shfl(v, k + j);
                u[j] = hj[(size_t)d[j] * 64 + l];
            }
            #pragma unroll
            for (int j = 0; j < 8; ++j) EDGE_BODY(k + j, u[j]);
        }
        for (; k < rem; ++k) {
            int dd = __shfl(v, k);
            unsigned uu = hj[(size_t)dd * 64 + l];
            EDGE_BODY(k, uu);
        }
        done += rem;
    }
#undef EDGE_BODY
    out[(size_t)n * 64 + l] = acc;   // covers ALL nodes -> no out memset needed
}

extern "C" void kernel_launch(void* const* d_in, const int* in_sizes, int n_in,
                              void* d_out, int out_size, void* d_ws, size_t ws_size,
                              hipStream_t stream) {
    const float* x     = (const float*)d_in[0];
    const int*   ei    = (const int*)d_in[1];
    const float* ea    = (const float*)d_in[2];
    const float* fc_w  = (const float*)d_in[3];
    const float* fc_b  = (const float*)d_in[4];
    const float* att_w = (const float*)d_in[5];
    const float* att_b = (const float*)d_in[6];
    float* out = (float*)d_out;

    const int N = in_sizes[0] / 128;  // 50000
    const int E = in_sizes[2] / 16;   // 800000

    // ws layout (256B-aligned segments), total ~55 MB:
    // ai f32[N*64] | hj u32[N*64] | count[N] | start[N] | sd int[E] | eaS u32[E*8]
    char* p = (char*)d_ws;
    auto align256 = [](size_t v) { return (v + 255) & ~(size_t)255; };
    float*    ai    = (float*)p;        p += align256((size_t)N * 64 * 4);
    unsigned* hj    = (unsigned*)p;     p += align256((size_t)N * 64 * 4);
    int*      count = (int*)p;          p += align256((size_t)N * 4);
    int*      startp= (int*)p;          p += align256((size_t)N * 4);
    int*      sd    = (int*)p;          p += align256((size_t)E * 4);
    uint4*    eaS   = (uint4*)p;

    hipMemsetAsync(count, 0, (size_t)N * sizeof(int), stream);

    node_kernel<<<512, 256, 0, stream>>>(x, fc_w, fc_b, att_w, att_b, ai, hj, N);
    hist_kernel<<<1024, 256, 0, stream>>>(ei, count, E);
    scan_kernel<<<1, 1024, 0, stream>>>(count, startp, N);
    scatter_kernel<<<1024, 256, 0, stream>>>(ei, startp, sd, eaS,
                                             (const float4*)ea, E);
    csr_edge_kernel<<<(N + 3) / 4, 256, 0, stream>>>(
        sd, (const uint2*)eaS, startp, count, ai, hj, att_w, out, N);
}

// Round 10
// 253.611 us; speedup vs baseline: 1.0417x; 1.0417x over previous
//
#include <hip/hip_runtime.h>

// EdgeGATConv: h = x@fc_w^T + fc_b;  alpha = leaky_relu(Wi@h[src] + Wj@h[dst] + We@ea + att_b)
// out[src] += h[dst] * alpha
// N=50000, C=128, H=64, E_DIM=16, E=800000
//
// R10: R9 profile — csr_edge 89us (VALU-bound), pre-edge phase ~175us.
// Culprit: scatter's 36B/edge random writes (line-RMW ~205MB) + single-block
// scan. Fix: slim 8B scatter (R7-proven), random-READ reorder pass for ea
// (gathers don't RMW; writes coalesced), multi-block scan (R7-proven).

__device__ __forceinline__ unsigned bf16r(float f) {  // f32 -> bf16 bits (RNE)
    unsigned u = __float_as_uint(f);
    return (u + 0x7fffu + ((u >> 16) & 1u)) >> 16;
}
__device__ __forceinline__ float bf_lo(unsigned p) { return __uint_as_float(p << 16); }
__device__ __forceinline__ float bf_hi(unsigned p) { return __uint_as_float(p & 0xffff0000u); }

// ---------------- node kernel (R9 form, bf16-packed hj out) -----------------
__global__ __launch_bounds__(256) void node_kernel(
    const float* __restrict__ x,
    const float* __restrict__ fc_w, const float* __restrict__ fc_b,
    const float* __restrict__ att_w, const float* __restrict__ att_b,
    float* __restrict__ ai_out, unsigned* __restrict__ hj_out, int N)
{
    __shared__ __align__(16) float4 wF[64 * 32];  // fc_w rows [64][128]
    __shared__ __align__(16) float4 wI[64 * 16];  // att_w[:, 0:64]
    __shared__ __align__(16) float4 wJ[64 * 16];  // att_w[:, 64:128]
    __shared__ __align__(16) float xs[4][128];
    __shared__ __align__(16) float hs[4][64];

    const int t = threadIdx.x;
    for (int idx = t; idx < 64 * 32; idx += 256) {
        int l = idx >> 5, c = idx & 31;
        wF[l * 32 + (c ^ (l & 31))] =
            *reinterpret_cast<const float4*>(fc_w + l * 128 + c * 4);
    }
    for (int idx = t; idx < 64 * 16; idx += 256) {
        int l = idx >> 4, c = idx & 15;
        wI[l * 16 + (c ^ (l & 15))] =
            *reinterpret_cast<const float4*>(att_w + l * 144 + c * 4);
        wJ[l * 16 + (c ^ (l & 15))] =
            *reinterpret_cast<const float4*>(att_w + l * 144 + 64 + c * 4);
    }
    __syncthreads();

    const int w = t >> 6, l = t & 63;
    const float bF = fc_b[l];
    const float bA = att_b[l];   // fold att_b into a_i
    const int waveId = blockIdx.x * 4 + w;
    const int nWaves = gridDim.x * 4;

    for (int n = waveId; n < N; n += nWaves) {
        float2 xv = reinterpret_cast<const float2*>(x)[(size_t)n * 64 + l];
        xs[w][2 * l] = xv.x;
        xs[w][2 * l + 1] = xv.y;
        float acc = bF;
        #pragma unroll
        for (int c = 0; c < 32; ++c) {
            float4 wv = wF[l * 32 + (c ^ (l & 31))];
            float4 xc = *reinterpret_cast<const float4*>(&xs[w][c * 4]);
            acc = fmaf(wv.x, xc.x, acc);
            acc = fmaf(wv.y, xc.y, acc);
            acc = fmaf(wv.z, xc.z, acc);
            acc = fmaf(wv.w, xc.w, acc);
        }
        hs[w][l] = acc;
        float a2 = bA, a3 = 0.f;
        #pragma unroll
        for (int c = 0; c < 16; ++c) {
            float4 hvv = *reinterpret_cast<const float4*>(&hs[w][c * 4]);
            float4 wi = wI[l * 16 + (c ^ (l & 15))];
            float4 wj = wJ[l * 16 + (c ^ (l & 15))];
            a2 = fmaf(wi.x, hvv.x, a2); a2 = fmaf(wi.y, hvv.y, a2);
            a2 = fmaf(wi.z, hvv.z, a2); a2 = fmaf(wi.w, hvv.w, a2);
            a3 = fmaf(wj.x, hvv.x, a3); a3 = fmaf(wj.y, hvv.y, a3);
            a3 = fmaf(wj.z, hvv.z, a3); a3 = fmaf(wj.w, hvv.w, a3);
        }
        ai_out[(size_t)n * 64 + l] = a2;
        // pack {h, aj} as bf16 pair: low=h, high=aj -> one dword gather/edge
        hj_out[(size_t)n * 64 + l] = (bf16r(a3) << 16) | bf16r(acc);
    }
}

// ---------------- src histogram ---------------------------------------------
__global__ __launch_bounds__(256) void hist_kernel(
    const int* __restrict__ ei, int* __restrict__ count, int E)
{
    int i = blockIdx.x * 256 + threadIdx.x;
    int stride = gridDim.x * 256;
    for (; i < E; i += stride) atomicAdd(&count[ei[i]], 1);
}

// ---------------- multi-block scan (R7-proven) ------------------------------
__global__ __launch_bounds__(256) void scan1_kernel(
    const int* __restrict__ count, int* __restrict__ start,
    int* __restrict__ bsum, int N)
{
    __shared__ int wsum[4];
    const int t = threadIdx.x, blk = blockIdx.x;
    const int idx0 = blk * 1024 + t * 4;
    int c0 = 0, c1 = 0, c2 = 0, c3 = 0;
    if (idx0 + 3 < N) {
        int4 c = *reinterpret_cast<const int4*>(count + idx0);
        c0 = c.x; c1 = c.y; c2 = c.z; c3 = c.w;
    } else {
        if (idx0 + 0 < N) c0 = count[idx0 + 0];
        if (idx0 + 1 < N) c1 = count[idx0 + 1];
        if (idx0 + 2 < N) c2 = count[idx0 + 2];
    }
    const int s = c0 + c1 + c2 + c3;
    const int lane = t & 63, w = t >> 6;
    int v = s;
    #pragma unroll
    for (int off = 1; off < 64; off <<= 1) {
        int u = __shfl_up(v, off);
        if (lane >= off) v += u;
    }
    if (lane == 63) wsum[w] = v;
    __syncthreads();
    int base = 0;
    if (w > 0) base += wsum[0];
    if (w > 1) base += wsum[1];
    if (w > 2) base += wsum[2];
    const int excl = base + v - s;
    if (idx0 + 0 < N) start[idx0 + 0] = excl;
    if (idx0 + 1 < N) start[idx0 + 1] = excl + c0;
    if (idx0 + 2 < N) start[idx0 + 2] = excl + c0 + c1;
    if (idx0 + 3 < N) start[idx0 + 3] = excl + c0 + c1 + c2;
    if (t == 255) bsum[blk] = base + v;
}

__global__ void scan2_kernel(int* __restrict__ bsum, int nb)
{
    const int l = threadIdx.x;
    int v = (l < nb) ? bsum[l] : 0;
    int inc = v;
    #pragma unroll
    for (int off = 1; off < 64; off <<= 1) {
        int u = __shfl_up(inc, off);
        if (l >= off) inc += u;
    }
    if (l < nb) bsum[l] = inc - v;
}

__global__ __launch_bounds__(256) void scan3_kernel(
    int* __restrict__ start, const int* __restrict__ bsum, int N)
{
    const int blk = blockIdx.x;
    const int add = bsum[blk];
    #pragma unroll
    for (int q = 0; q < 4; ++q) {
        int i = blk * 1024 + q * 256 + threadIdx.x;
        if (i < N) start[i] += add;
    }
}

// ---------------- slim scatter: 8B/edge random write ------------------------
__global__ __launch_bounds__(256) void scatter_kernel(
    const int* __restrict__ ei, int* __restrict__ start,
    int2* __restrict__ sd, int E)
{
    int i = blockIdx.x * 256 + threadIdx.x;
    int stride = gridDim.x * 256;
    for (; i < E; i += stride) {
        int s = ei[i];
        int pos = atomicAdd(&start[s], 1);
        sd[pos] = make_int2(ei[E + i], i);   // {dst, eid}
    }
}

// -------- reorder: random READ of ea (no RMW), coalesced bf16 write ---------
__global__ __launch_bounds__(256) void reorder_kernel(
    const int2* __restrict__ sd, const float4* __restrict__ ea4,
    uint4* __restrict__ eaS, int E)
{
    int j = blockIdx.x * 256 + threadIdx.x;
    if (j >= E) return;
    int eid = sd[j].y;
    float4 r0 = ea4[(size_t)eid * 4 + 0], r1 = ea4[(size_t)eid * 4 + 1];
    float4 r2 = ea4[(size_t)eid * 4 + 2], r3 = ea4[(size_t)eid * 4 + 3];
    uint4 q0 = make_uint4((bf16r(r0.y) << 16) | bf16r(r0.x),
                          (bf16r(r0.w) << 16) | bf16r(r0.z),
                          (bf16r(r1.y) << 16) | bf16r(r1.x),
                          (bf16r(r1.w) << 16) | bf16r(r1.z));
    uint4 q1 = make_uint4((bf16r(r2.y) << 16) | bf16r(r2.x),
                          (bf16r(r2.w) << 16) | bf16r(r2.z),
                          (bf16r(r3.y) << 16) | bf16r(r3.x),
                          (bf16r(r3.w) << 16) | bf16r(r3.z));
    eaS[(size_t)j * 2 + 0] = q0;
    eaS[(size_t)j * 2 + 1] = q1;
}

// --------- CSR edge kernel (R9-identical compute; sd is int2, use .x) -------
__global__ __launch_bounds__(256) void csr_edge_kernel(
    const int2* __restrict__ sd, const uint2* __restrict__ eaS2,
    const int* __restrict__ endp, const int* __restrict__ count,
    const float* __restrict__ ai, const unsigned* __restrict__ hj,
    const float* __restrict__ att_w, float* __restrict__ out, int N)
{
    __shared__ uint2 eas[4][256];     // per wave: 64 edges x 8 u32 (bf16 rows)
    __shared__ float weS[64][17];     // att_w[:,128:144], padded

    const int t = threadIdx.x, w = t >> 6, l = t & 63;
    for (int idx = t; idx < 1024; idx += 256)
        weS[idx >> 4][idx & 15] = att_w[(idx >> 4) * 144 + 128 + (idx & 15)];
    __syncthreads();

    const int n = blockIdx.x * 4 + w;
    if (n >= N) return;

    float we[16];
    #pragma unroll
    for (int k = 0; k < 16; ++k) we[k] = weS[l][k];

    const int deg = count[n];
    const int base = endp[n] - deg;    // endp was advanced by scatter
    const float aiv = ai[(size_t)n * 64 + l];
    float acc = 0.f;

#define EDGE_BODY(KK, UU)                                                      \
    {                                                                          \
        float pre = aiv + bf_hi(UU);                                           \
        _Pragma("unroll") for (int r = 0; r < 4; ++r) {                        \
            uint2 q = eas[w][(KK) * 4 + r];                                    \
            pre = fmaf(we[r * 4 + 0], bf_lo(q.x), pre);                        \
            pre = fmaf(we[r * 4 + 1], bf_hi(q.x), pre);                        \
            pre = fmaf(we[r * 4 + 2], bf_lo(q.y), pre);                        \
            pre = fmaf(we[r * 4 + 3], bf_hi(q.y), pre);                        \
        }                                                                      \
        float alpha = pre > 0.f ? pre : 0.2f * pre;                            \
        acc = fmaf(bf_lo(UU), alpha, acc);                                     \
    }

    int done = 0;
    while (done < deg) {
        const int rem = min(64, deg - done);
        int v = 0;
        if (l < rem) v = sd[base + done + l].x;
        for (int f = l; f < rem * 4; f += 64)          // stage ea rows (stream)
            eas[w][f] = eaS2[(size_t)(base + done) * 4 + f];
        int k = 0;
        for (; k + 8 <= rem; k += 8) {                 // 8 gathers in flight
            int d[8]; unsigned u[8];
            #pragma unroll
            for (int j = 0; j < 8; ++j) {
                d[j] = __shfl(v, k + j);
                u[j] = hj[(size_t)d[j] * 64 + l];
            }
            #pragma unroll
            for (int j = 0; j < 8; ++j) EDGE_BODY(k + j, u[j]);
        }
        for (; k < rem; ++k) {
            int dd = __shfl(v, k);
            unsigned uu = hj[(size_t)dd * 64 + l];
            EDGE_BODY(k, uu);
        }
        done += rem;
    }
#undef EDGE_BODY
    out[(size_t)n * 64 + l] = acc;   // covers ALL nodes -> no out memset needed
}

extern "C" void kernel_launch(void* const* d_in, const int* in_sizes, int n_in,
                              void* d_out, int out_size, void* d_ws, size_t ws_size,
                              hipStream_t stream) {
    const float* x     = (const float*)d_in[0];
    const int*   ei    = (const int*)d_in[1];
    const float* ea    = (const float*)d_in[2];
    const float* fc_w  = (const float*)d_in[3];
    const float* fc_b  = (const float*)d_in[4];
    const float* att_w = (const float*)d_in[5];
    const float* att_b = (const float*)d_in[6];
    float* out = (float*)d_out;

    const int N = in_sizes[0] / 128;  // 50000
    const int E = in_sizes[2] / 16;   // 800000

    // ws layout (256B-aligned), ~58.4 MB total:
    // ai f32[N*64] | hj u32[N*64] | count[N] | start[N] | bsum[64]
    // | sd int2[E] | eaS u32[E*8]
    char* p = (char*)d_ws;
    auto align256 = [](size_t v) { return (v + 255) & ~(size_t)255; };
    float*    ai    = (float*)p;        p += align256((size_t)N * 64 * 4);
    unsigned* hj    = (unsigned*)p;     p += align256((size_t)N * 64 * 4);
    int*      count = (int*)p;          p += align256((size_t)N * 4);
    int*      startp= (int*)p;          p += align256((size_t)N * 4);
    int*      bsum  = (int*)p;          p += align256(64 * 4);
    int2*     sd    = (int2*)p;         p += align256((size_t)E * 8);
    uint4*    eaS   = (uint4*)p;

    hipMemsetAsync(count, 0, (size_t)N * sizeof(int), stream);

    node_kernel<<<512, 256, 0, stream>>>(x, fc_w, fc_b, att_w, att_b, ai, hj, N);
    hist_kernel<<<1024, 256, 0, stream>>>(ei, count, E);

    const int nb1 = (N + 1023) / 1024;
    scan1_kernel<<<nb1, 256, 0, stream>>>(count, startp, bsum, N);
    scan2_kernel<<<1, 64, 0, stream>>>(bsum, nb1);
    scan3_kernel<<<nb1, 256, 0, stream>>>(startp, bsum, N);

    scatter_kernel<<<1024, 256, 0, stream>>>(ei, startp, sd, E);
    reorder_kernel<<<(E + 255) / 256, 256, 0, stream>>>(sd, (const float4*)ea, eaS, E);

    csr_edge_kernel<<<(N + 3) / 4, 256, 0, stream>>>(
        sd, (const uint2*)eaS, startp, count, ai, hj, att_w, out, N);
}

// Round 12
// 248.438 us; speedup vs baseline: 1.0634x; 1.0208x over previous
//
#include <hip/hip_runtime.h>

// EdgeGATConv: h = x@fc_w^T + fc_b;  alpha = leaky_relu(Wi@h[src] + Wj@h[dst] + We@ea + att_b)
// out[src] += h[dst] * alpha
// N=50000, C=128, H=64, E_DIM=16, E=800000
//
// R12: R11's divergent-shfl ea staging corrupted results (absmax 6.8). Rebuilt
// from proven patterns only: lane-owns-edge convergent staging (no shfl),
// explicit lgkmcnt(0)+sched_barrier after LDS writes (R1-R5 idiom), padded
// LDS rows. Rest identical to R10 minus the reorder pass.

__device__ __forceinline__ unsigned bf16r(float f) {  // f32 -> bf16 bits (RNE)
    unsigned u = __float_as_uint(f);
    return (u + 0x7fffu + ((u >> 16) & 1u)) >> 16;
}
__device__ __forceinline__ float bf_lo(unsigned p) { return __uint_as_float(p << 16); }
__device__ __forceinline__ float bf_hi(unsigned p) { return __uint_as_float(p & 0xffff0000u); }

// ---------------- node kernel (R9 form, bf16-packed hj out) -----------------
__global__ __launch_bounds__(256) void node_kernel(
    const float* __restrict__ x,
    const float* __restrict__ fc_w, const float* __restrict__ fc_b,
    const float* __restrict__ att_w, const float* __restrict__ att_b,
    float* __restrict__ ai_out, unsigned* __restrict__ hj_out, int N)
{
    __shared__ __align__(16) float4 wF[64 * 32];  // fc_w rows [64][128]
    __shared__ __align__(16) float4 wI[64 * 16];  // att_w[:, 0:64]
    __shared__ __align__(16) float4 wJ[64 * 16];  // att_w[:, 64:128]
    __shared__ __align__(16) float xs[4][128];
    __shared__ __align__(16) float hs[4][64];

    const int t = threadIdx.x;
    for (int idx = t; idx < 64 * 32; idx += 256) {
        int l = idx >> 5, c = idx & 31;
        wF[l * 32 + (c ^ (l & 31))] =
            *reinterpret_cast<const float4*>(fc_w + l * 128 + c * 4);
    }
    for (int idx = t; idx < 64 * 16; idx += 256) {
        int l = idx >> 4, c = idx & 15;
        wI[l * 16 + (c ^ (l & 15))] =
            *reinterpret_cast<const float4*>(att_w + l * 144 + c * 4);
        wJ[l * 16 + (c ^ (l & 15))] =
            *reinterpret_cast<const float4*>(att_w + l * 144 + 64 + c * 4);
    }
    __syncthreads();

    const int w = t >> 6, l = t & 63;
    const float bF = fc_b[l];
    const float bA = att_b[l];   // fold att_b into a_i
    const int waveId = blockIdx.x * 4 + w;
    const int nWaves = gridDim.x * 4;

    for (int n = waveId; n < N; n += nWaves) {
        float2 xv = reinterpret_cast<const float2*>(x)[(size_t)n * 64 + l];
        xs[w][2 * l] = xv.x;
        xs[w][2 * l + 1] = xv.y;
        float acc = bF;
        #pragma unroll
        for (int c = 0; c < 32; ++c) {
            float4 wv = wF[l * 32 + (c ^ (l & 31))];
            float4 xc = *reinterpret_cast<const float4*>(&xs[w][c * 4]);
            acc = fmaf(wv.x, xc.x, acc);
            acc = fmaf(wv.y, xc.y, acc);
            acc = fmaf(wv.z, xc.z, acc);
            acc = fmaf(wv.w, xc.w, acc);
        }
        hs[w][l] = acc;
        float a2 = bA, a3 = 0.f;
        #pragma unroll
        for (int c = 0; c < 16; ++c) {
            float4 hvv = *reinterpret_cast<const float4*>(&hs[w][c * 4]);
            float4 wi = wI[l * 16 + (c ^ (l & 15))];
            float4 wj = wJ[l * 16 + (c ^ (l & 15))];
            a2 = fmaf(wi.x, hvv.x, a2); a2 = fmaf(wi.y, hvv.y, a2);
            a2 = fmaf(wi.z, hvv.z, a2); a2 = fmaf(wi.w, hvv.w, a2);
            a3 = fmaf(wj.x, hvv.x, a3); a3 = fmaf(wj.y, hvv.y, a3);
            a3 = fmaf(wj.z, hvv.z, a3); a3 = fmaf(wj.w, hvv.w, a3);
        }
        ai_out[(size_t)n * 64 + l] = a2;
        // pack {h, aj} as bf16 pair: low=h, high=aj -> one dword gather/edge
        hj_out[(size_t)n * 64 + l] = (bf16r(a3) << 16) | bf16r(acc);
    }
}

// ---------------- src histogram ---------------------------------------------
__global__ __launch_bounds__(256) void hist_kernel(
    const int* __restrict__ ei, int* __restrict__ count, int E)
{
    int i = blockIdx.x * 256 + threadIdx.x;
    int stride = gridDim.x * 256;
    for (; i < E; i += stride) atomicAdd(&count[ei[i]], 1);
}

// ---------------- multi-block scan (R7-proven) ------------------------------
__global__ __launch_bounds__(256) void scan1_kernel(
    const int* __restrict__ count, int* __restrict__ start,
    int* __restrict__ bsum, int N)
{
    __shared__ int wsum[4];
    const int t = threadIdx.x, blk = blockIdx.x;
    const int idx0 = blk * 1024 + t * 4;
    int c0 = 0, c1 = 0, c2 = 0, c3 = 0;
    if (idx0 + 3 < N) {
        int4 c = *reinterpret_cast<const int4*>(count + idx0);
        c0 = c.x; c1 = c.y; c2 = c.z; c3 = c.w;
    } else {
        if (idx0 + 0 < N) c0 = count[idx0 + 0];
        if (idx0 + 1 < N) c1 = count[idx0 + 1];
        if (idx0 + 2 < N) c2 = count[idx0 + 2];
    }
    const int s = c0 + c1 + c2 + c3;
    const int lane = t & 63, w = t >> 6;
    int v = s;
    #pragma unroll
    for (int off = 1; off < 64; off <<= 1) {
        int u = __shfl_up(v, off);
        if (lane >= off) v += u;
    }
    if (lane == 63) wsum[w] = v;
    __syncthreads();
    int base = 0;
    if (w > 0) base += wsum[0];
    if (w > 1) base += wsum[1];
    if (w > 2) base += wsum[2];
    const int excl = base + v - s;
    if (idx0 + 0 < N) start[idx0 + 0] = excl;
    if (idx0 + 1 < N) start[idx0 + 1] = excl + c0;
    if (idx0 + 2 < N) start[idx0 + 2] = excl + c0 + c1;
    if (idx0 + 3 < N) start[idx0 + 3] = excl + c0 + c1 + c2;
    if (t == 255) bsum[blk] = base + v;
}

__global__ void scan2_kernel(int* __restrict__ bsum, int nb)
{
    const int l = threadIdx.x;
    int v = (l < nb) ? bsum[l] : 0;
    int inc = v;
    #pragma unroll
    for (int off = 1; off < 64; off <<= 1) {
        int u = __shfl_up(inc, off);
        if (l >= off) inc += u;
    }
    if (l < nb) bsum[l] = inc - v;
}

__global__ __launch_bounds__(256) void scan3_kernel(
    int* __restrict__ start, const int* __restrict__ bsum, int N)
{
    const int blk = blockIdx.x;
    const int add = bsum[blk];
    #pragma unroll
    for (int q = 0; q < 4; ++q) {
        int i = blk * 1024 + q * 256 + threadIdx.x;
        if (i < N) start[i] += add;
    }
}

// ---------------- slim scatter: 8B/edge random write ------------------------
__global__ __launch_bounds__(256) void scatter_kernel(
    const int* __restrict__ ei, int* __restrict__ start,
    int2* __restrict__ sd, int E)
{
    int i = blockIdx.x * 256 + threadIdx.x;
    int stride = gridDim.x * 256;
    for (; i < E; i += stride) {
        int s = ei[i];
        int pos = atomicAdd(&start[s], 1);
        sd[pos] = make_int2(ei[E + i], i);   // {dst, eid}
    }
}

// --------- CSR edge kernel: 1 dword hj gather/edge + raw ea lane-staged -----
__global__ __launch_bounds__(256) void csr_edge_kernel(
    const int2* __restrict__ sd, const float4* __restrict__ ea4,
    const int* __restrict__ endp, const int* __restrict__ count,
    const float* __restrict__ ai, const unsigned* __restrict__ hj,
    const float* __restrict__ att_w, float* __restrict__ out, int N)
{
    // [5] pad: 80B row stride spreads the 64B-stride write conflict to ~8-way
    __shared__ __align__(16) float4 eas4[4][64][5];  // per wave: 64 edges x 16 f32
    __shared__ float weS[64][17];                    // att_w[:,128:144], padded

    const int t = threadIdx.x, w = t >> 6, l = t & 63;
    for (int idx = t; idx < 1024; idx += 256)
        weS[idx >> 4][idx & 15] = att_w[(idx >> 4) * 144 + 128 + (idx & 15)];
    __syncthreads();

    const int n = blockIdx.x * 4 + w;
    if (n >= N) return;

    float we[16];
    #pragma unroll
    for (int k = 0; k < 16; ++k) we[k] = weS[l][k];

    const int deg = count[n];
    const int base = endp[n] - deg;    // endp was advanced by scatter
    const float aiv = ai[(size_t)n * 64 + l];
    float acc = 0.f;

#define EDGE_BODY(KK, UU)                                                      \
    {                                                                          \
        float4 v0 = eas4[w][KK][0];                                            \
        float4 v1 = eas4[w][KK][1];                                            \
        float4 v2 = eas4[w][KK][2];                                            \
        float4 v3 = eas4[w][KK][3];                                            \
        float pre = aiv + bf_hi(UU);                                           \
        pre = fmaf(we[0], v0.x, pre);  pre = fmaf(we[1], v0.y, pre);           \
        pre = fmaf(we[2], v0.z, pre);  pre = fmaf(we[3], v0.w, pre);           \
        pre = fmaf(we[4], v1.x, pre);  pre = fmaf(we[5], v1.y, pre);           \
        pre = fmaf(we[6], v1.z, pre);  pre = fmaf(we[7], v1.w, pre);           \
        pre = fmaf(we[8], v2.x, pre);  pre = fmaf(we[9], v2.y, pre);           \
        pre = fmaf(we[10], v2.z, pre); pre = fmaf(we[11], v2.w, pre);          \
        pre = fmaf(we[12], v3.x, pre); pre = fmaf(we[13], v3.y, pre);          \
        pre = fmaf(we[14], v3.z, pre); pre = fmaf(we[15], v3.w, pre);          \
        float alpha = pre > 0.f ? pre : 0.2f * pre;                            \
        acc = fmaf(bf_lo(UU), alpha, acc);                                     \
    }

    int done = 0;
    while (done < deg) {
        const int rem = min(64, deg - done);
        int2 v = make_int2(0, 0);
        if (l < rem) v = sd[base + done + l];
        // lane l stages its OWN edge's full 64B ea row (convergent, no shfl;
        // lanes >= rem harmlessly stage edge 0's row, never read)
        {
            const float4* er = ea4 + (size_t)v.y * 4;
            float4 r0 = er[0], r1 = er[1], r2 = er[2], r3 = er[3];
            eas4[w][l][0] = r0;
            eas4[w][l][1] = r1;
            eas4[w][l][2] = r2;
            eas4[w][l][3] = r3;
        }
        // make LDS writes visible to cross-lane reads before compute
        asm volatile("s_waitcnt lgkmcnt(0)" ::: "memory");
        __builtin_amdgcn_sched_barrier(0);

        int k = 0;
        for (; k + 8 <= rem; k += 8) {                 // 8 hj gathers in flight
            int d[8]; unsigned u[8];
            #pragma unroll
            for (int j = 0; j < 8; ++j) {
                d[j] = __shfl(v.x, k + j);
                u[j] = hj[(size_t)d[j] * 64 + l];
            }
            #pragma unroll
            for (int j = 0; j < 8; ++j) EDGE_BODY(k + j, u[j]);
        }
        for (; k < rem; ++k) {
            int dd = __shfl(v.x, k);
            unsigned uu = hj[(size_t)dd * 64 + l];
            EDGE_BODY(k, uu);
        }
        done += rem;
    }
#undef EDGE_BODY
    out[(size_t)n * 64 + l] = acc;   // covers ALL nodes -> no out memset needed
}

extern "C" void kernel_launch(void* const* d_in, const int* in_sizes, int n_in,
                              void* d_out, int out_size, void* d_ws, size_t ws_size,
                              hipStream_t stream) {
    const float* x     = (const float*)d_in[0];
    const int*   ei    = (const int*)d_in[1];
    const float* ea    = (const float*)d_in[2];
    const float* fc_w  = (const float*)d_in[3];
    const float* fc_b  = (const float*)d_in[4];
    const float* att_w = (const float*)d_in[5];
    const float* att_b = (const float*)d_in[6];
    float* out = (float*)d_out;

    const int N = in_sizes[0] / 128;  // 50000
    const int E = in_sizes[2] / 16;   // 800000

    // ws layout (256B-aligned), ~32.8 MB total:
    // ai f32[N*64] | hj u32[N*64] | count[N] | start[N] | bsum[64] | sd int2[E]
    char* p = (char*)d_ws;
    auto align256 = [](size_t v) { return (v + 255) & ~(size_t)255; };
    float*    ai    = (float*)p;        p += align256((size_t)N * 64 * 4);
    unsigned* hj    = (unsigned*)p;     p += align256((size_t)N * 64 * 4);
    int*      count = (int*)p;          p += align256((size_t)N * 4);
    int*      startp= (int*)p;          p += align256((size_t)N * 4);
    int*      bsum  = (int*)p;          p += align256(64 * 4);
    int2*     sd    = (int2*)p;

    hipMemsetAsync(count, 0, (size_t)N * sizeof(int), stream);

    node_kernel<<<512, 256, 0, stream>>>(x, fc_w, fc_b, att_w, att_b, ai, hj, N);
    hist_kernel<<<1024, 256, 0, stream>>>(ei, count, E);

    const int nb1 = (N + 1023) / 1024;
    scan1_kernel<<<nb1, 256, 0, stream>>>(count, startp, bsum, N);
    scan2_kernel<<<1, 64, 0, stream>>>(bsum, nb1);
    scan3_kernel<<<nb1, 256, 0, stream>>>(startp, bsum, N);

    scatter_kernel<<<1024, 256, 0, stream>>>(ei, startp, sd, E);

    csr_edge_kernel<<<(N + 3) / 4, 256, 0, stream>>>(
        sd, (const float4*)ea, startp, count, ai, hj, att_w, out, N);
}